// Round 18
// baseline (87.488 us; speedup 1.0000x reference)
//
#include <hip/hip_runtime.h>

typedef __attribute__((ext_vector_type(8))) short short8;
typedef __attribute__((ext_vector_type(4))) float f32x4;
typedef __attribute__((ext_vector_type(4))) unsigned short us4;

constexpr int NB = 8, NC = 256, IH = 64, IW = 96;
constexpr int PATCH = 21, RAD = 10;
constexpr int TI = 8, TJ = 8;            // pixel tile
constexpr int WIN = 28, NWIN = 784;      // x2 window per tile
constexpr int KC = 32, NKS = NC / KC;    // channel chunking
constexpr int PLANE = IH * IW;
constexpr int PH = IH + 2 * RAD, PW = IW + 2 * RAD;   // 84 x 116 padded x2
constexpr int NCHB = 3136;               // chunks per buffer: waves 0-6 x384 + wave7 x448
constexpr int ASTR = IH * IW * KC;       // per-ks stride in x1k (elements)
constexpr int BSTR = PH * PW * KC;       // per-ks stride in x2k (elements)
constexpr size_t X1T_ELEMS = (size_t)NB * NKS * ASTR;   // 12.58M
constexpr size_t X2P_ELEMS = (size_t)NB * NKS * BSTR;   // 19.96M
constexpr int GSTR = 65;                 // G-chunk m-stride (floats)
constexpr int X1BLKS = NB * IH * 8;      // 4096 prepass blocks for x1
constexpr int X2BLKS = NB * PH * 8;      // 5376 prepass blocks for x2

__device__ __forceinline__ unsigned short f2bf(float f) {
  unsigned u = __builtin_bit_cast(unsigned, f);
  u += 0x7fffu + ((u >> 16) & 1u);       // RNE
  return (unsigned short)(u >> 16);
}

// ---- merged pre-pass (R16-validated, BW-bound): NCHW fp32 -> K-major bf16 ----
__global__ __launch_bounds__(256) void prepass_kmajor(
    const float* __restrict__ x1, const float* __restrict__ x2,
    unsigned short* __restrict__ x1k, unsigned short* __restrict__ x2k) {
  __shared__ float lsf[32 * 97];
  const int t = threadIdx.x;
  if (blockIdx.x < X1BLKS) {
    const int blk = blockIdx.x;          // b*512 + i*8 + ct
    const int ct = blk & 7, i = (blk >> 3) & 63, b = blk >> 9;
    const int c0 = ct * 32;
    const float* sp = x1 + ((size_t)b * NC + c0) * PLANE + (size_t)i * IW;
#pragma unroll
    for (int k = 0; k < 3; ++k) {        // 768 float4
      int idx = k * 256 + t;
      int c = idx / 24, j4 = idx - c * 24;
      f32x4 v = *(const f32x4*)(sp + (size_t)c * PLANE + 4 * j4);
      float* lp = &lsf[c * 97 + 4 * j4];
      lp[0] = v[0]; lp[1] = v[1]; lp[2] = v[2]; lp[3] = v[3];
    }
    __syncthreads();
    unsigned short* dp = x1k + (((size_t)(b * NKS + ct) * IH + i) * IW) * KC;
#pragma unroll
    for (int k = 0; k < 3; ++k) {
      int o = k * 256 + t;
      int j = o >> 3, cq = o & 7;
      us4 v = {f2bf(lsf[(cq * 4 + 0) * 97 + j]), f2bf(lsf[(cq * 4 + 1) * 97 + j]),
               f2bf(lsf[(cq * 4 + 2) * 97 + j]), f2bf(lsf[(cq * 4 + 3) * 97 + j])};
      *(us4*)&dp[(size_t)j * KC + cq * 4] = v;
    }
  } else {
    const int blk = blockIdx.x - X1BLKS; // b*(84*8) + i*8 + ct
    const int ct = blk & 7, i = (blk >> 3) % PH, b = blk / (PH * 8);
    const int c0 = ct * 32;
    const int isrc = i - RAD;
    const bool rowok = (unsigned)isrc < (unsigned)IH;
    if (rowok) {
      const float* sp = x2 + ((size_t)b * NC + c0) * PLANE + (size_t)isrc * IW;
#pragma unroll
      for (int k = 0; k < 3; ++k) {
        int idx = k * 256 + t;
        int c = idx / 24, j4 = idx - c * 24;
        f32x4 v = *(const f32x4*)(sp + (size_t)c * PLANE + 4 * j4);
        float* lp = &lsf[c * 97 + 4 * j4];
        lp[0] = v[0]; lp[1] = v[1]; lp[2] = v[2]; lp[3] = v[3];
      }
    }
    __syncthreads();
    unsigned short* dp = x2k + (((size_t)(b * NKS + ct) * PH + i) * PW) * KC;
#pragma unroll
    for (int k = 0; k < 4; ++k) {
      int o = k * 256 + t;
      if (o < PW * 8) {
        int j = o >> 3, cq = o & 7;
        int jsrc = j - RAD;
        us4 v = {0, 0, 0, 0};
        if (rowok && (unsigned)jsrc < (unsigned)IW)
          v = us4{f2bf(lsf[(cq * 4 + 0) * 97 + jsrc]), f2bf(lsf[(cq * 4 + 1) * 97 + jsrc]),
                  f2bf(lsf[(cq * 4 + 2) * 97 + jsrc]), f2bf(lsf[(cq * 4 + 3) * 97 + jsrc])};
        *(us4*)&dp[(size_t)j * KC + cq * 4] = v;
      }
    }
  }
}

// ---- main: 8 wave-autonomous pipelines, NO K-loop barriers, 2-AHEAD prefetch ----
// R17 safety class (all hazards per-wave program-order + counted vmcnt), but:
//  - triple-buffered wave-private staging (stage ks+2 while computing ks)
//  - exact col-tile split: waves 0-6 own 6 tiles (384 chunks), wave 7 owns 7
//    (448) -> 3136 chunks/buffer x 3 = 150.5 KB LDS, no duplicate tiles
//  - A-fragments: 3-set register rotation (load A(ks+2) at iter ks)
__global__ __launch_bounds__(512, 2) void corr_wavepipe2(
    const unsigned short* __restrict__ x1k, const unsigned short* __restrict__ x2k,
    float* __restrict__ out) {
  __shared__ __attribute__((aligned(16))) unsigned short ls[3 * NCHB * 8];  // 150528 B

  const int t = threadIdx.x, lane = t & 63, wv = t >> 6;   // wv 0..7
  const int bid = blockIdx.x;
  const int b = bid & 7;                 // batch -> XCD locality
  const int tile = bid >> 3;
  const int ti = tile / 12, tj = tile - ti * 12;
  const int i0 = ti * TI, j0 = tj * TJ;
  const int cbeg = 6 * wv;               // waves 0-6: tiles 6wv..6wv+5; wave 7: 42..48
  const int nt = (wv == 7) ? 7 : 6;      // col-tiles owned (wave-uniform)
  const int qk = lane >> 4, lr = lane & 15;
  const int woff = 384 * wv;             // wave-private chunk offset in each buffer

  const unsigned short* x1b = x1k + (size_t)b * NKS * ASTR;
  const unsigned short* x2b = x2k + (size_t)b * NKS * BSTR;

  // per-wave B sources: local chunk c = s*64 + lane; inverse of the validated
  // slot swizzle slot(w,c4) = (4w+c4)^(w&7); global position n = 96*wv + w.
  const unsigned short* srcp[7];
#pragma unroll
  for (int s = 0; s < 7; ++s) {
    int c = s * 64 + lane;
    int w = ((c >> 3) << 1) | (((c >> 2) ^ (c >> 4)) & 1);
    int c4 = (c & 3) ^ (w & 3);
    int n = 96 * wv + w;                 // wave 7 reaches n=783 max (s=6)
    if (n > 783) n = 783;                // never executed for issuing waves; safety
    int wi = n / WIN, wj = n - wi * WIN;
    srcp[s] = x2b + ((size_t)(i0 + wi) * PW + (j0 + wj)) * KC + c4 * 8;
  }
  // per-lane A-frag base (R9/R17-validated addressing): frag a = pixels 16a+lr
  const unsigned short* srcA =
      x1b + ((size_t)(i0 + (lr >> 3)) * IW + (j0 + (lr & 7))) * KC + qk * 8;
  constexpr size_t AOFF = (size_t)2 * IW * KC;

  f32x4 acc[4][7];
#pragma unroll
  for (int a = 0; a < 4; ++a)
#pragma unroll
    for (int cc = 0; cc < 7; ++cc) acc[a][cc] = (f32x4){0.f, 0.f, 0.f, 0.f};

  short8 aA0, aA1, aA2, aA3, aB0, aB1, aB2, aB3, aC0, aC1, aC2, aC3;  // 3 A sets

#define ALOAD(S, KS)                                                                \
  {                                                                                 \
    const unsigned short* ap = srcA + (size_t)(KS) * ASTR;                          \
    a##S##0 = *(const short8*)(ap);                                                 \
    a##S##1 = *(const short8*)(ap + AOFF);                                          \
    a##S##2 = *(const short8*)(ap + 2 * AOFF);                                      \
    a##S##3 = *(const short8*)(ap + 3 * AOFF);                                      \
  }

// wave-private stage: 6 instr (+1 for wave 7); group size 10 (wv<7) / 11 (wv7)
// including the 4 A-loads issued in the same group.
#define STAGEW(BUF, KS)                                                             \
  {                                                                                 \
    unsigned short* lb = &ls[((BUF) * NCHB + woff) * 8];                            \
    _Pragma("unroll")                                                               \
    for (int s = 0; s < 6; ++s)                                                     \
      __builtin_amdgcn_global_load_lds(                                             \
          (const void*)(srcp[s] + (size_t)(KS) * BSTR),                             \
          (void*)(lb + s * 512), 16, 0, 0);                                         \
    if (wv == 7)                                                                    \
      __builtin_amdgcn_global_load_lds(                                             \
          (const void*)(srcp[6] + (size_t)(KS) * BSTR),                             \
          (void*)(lb + 6 * 512), 16, 0, 0);                                         \
  }

#define COMPUTE(BUF, S)                                                             \
  {                                                                                 \
    const unsigned short* lb = &ls[((BUF) * NCHB + woff) * 8];                      \
    _Pragma("unroll")                                                               \
    for (int cc = 0; cc < 7; ++cc) {                                                \
      if (cc < nt) {                                                                \
        int wl = 16 * cc + lr;                                                      \
        int slot = (4 * wl + qk) ^ (lr & 7);                                        \
        short8 bf = *(const short8*)(lb + slot * 8);                                \
        acc[0][cc] = __builtin_amdgcn_mfma_f32_16x16x32_bf16(a##S##0, bf, acc[0][cc], 0, 0, 0); \
        acc[1][cc] = __builtin_amdgcn_mfma_f32_16x16x32_bf16(a##S##1, bf, acc[1][cc], 0, 0, 0); \
        acc[2][cc] = __builtin_amdgcn_mfma_f32_16x16x32_bf16(a##S##2, bf, acc[2][cc], 0, 0, 0); \
        acc[3][cc] = __builtin_amdgcn_mfma_f32_16x16x32_bf16(a##S##3, bf, acc[3][cc], 0, 0, 0); \
      }                                                                             \
    }                                                                               \
  }

  // prologue: 3 groups {A(k), S(k)}, fenced so vmcnt group counting is exact
  ALOAD(A, 0)
  STAGEW(0, 0)
  asm volatile("" ::: "memory");
  ALOAD(B, 1)
  STAGEW(1, 1)
  asm volatile("" ::: "memory");
  ALOAD(C, 2)
  STAGEW(2, 2)

  // iter ks: issue group {A(ks+2), S(ks+2)->buf[(ks+2)%3]} (WAR self-ordered:
  // this wave read that buffer at iter ks-1, program order); counted vmcnt
  // leaves the newest 2 groups (20|22) -> drains {S(ks), A(ks)}; compute.
  // No cross-wave hazards anywhere in the K-loop.
#define ITER(KS, SL, SC, VMA, VMB)                                                  \
  if ((KS) < 6) { ALOAD(SL, (KS) + 2) STAGEW(((KS) + 2) % 3, (KS) + 2) }            \
  if (wv == 7) { asm volatile("s_waitcnt vmcnt(" #VMB ")" ::: "memory"); }          \
  else         { asm volatile("s_waitcnt vmcnt(" #VMA ")" ::: "memory"); }          \
  COMPUTE((KS) % 3, SC)

  ITER(0, C, A, 20, 22)
  ITER(1, A, B, 20, 22)
  ITER(2, B, C, 20, 22)
  ITER(3, C, A, 20, 22)
  ITER(4, A, B, 20, 22)
  ITER(5, B, C, 20, 22)
  ITER(6, C, A, 10, 11)
  ITER(7, C, B, 0, 0)
#undef ITER
#undef COMPUTE
#undef STAGEW
#undef ALOAD

  // ---- epilogue: LDS diagonal transpose -> coalesced 32B stores ----
  // (R15-validated; ownership now exact 49 tiles, guard cc<nt, no dedup skip)
  float* gf = (float*)ls;
#pragma unroll
  for (int ch = 0; ch < 2; ++ch) {
    __syncthreads();                     // all waves' K-loops done; reads drained
    const int n0 = ch ? 384 : 0;
#pragma unroll
    for (int a = 0; a < 4; ++a)
#pragma unroll
      for (int cc = 0; cc < 7; ++cc) {
        int ccg = cbeg + cc;
        if (cc < nt && (ch ? (ccg >= 24) : (ccg <= 24))) {
          int nl = 16 * ccg + lr - n0;
          int mb = 16 * a + 4 * qk;
          float* gp = &gf[nl * GSTR + mb];
          gp[0] = acc[a][cc][0]; gp[1] = acc[a][cc][1];
          gp[2] = acc[a][cc][2]; gp[3] = acc[a][cc][3];
        }
      }
    __syncthreads();
    for (int s = t; s < 1764; s += 512) {
      int pidx = s / 21, pj = s - pidx * 21;
      int ii = 0, rem = pidx, stop = 0;
#pragma unroll
      for (int k = 0; k < 7; ++k) {
        int cnt = ch ? (7 + k) : (14 - k);
        int go = (!stop) && (rem >= cnt);
        rem -= go ? cnt : 0;
        ii += go;
        stop |= !go;
      }
      int pi = ch ? (14 - ii + rem) : rem;
      int nl = 28 * (pi + ii) + pj - n0;
      int ms = 8 * ii;
      float g[8];
#pragma unroll
      for (int e = 0; e < 8; ++e) g[e] = gf[(nl + e) * GSTR + ms + e];
      float* op = out + ((((size_t)b * PATCH + pi) * PATCH + pj) * IH + (i0 + ii)) * IW + j0;
      f32x4 v0 = {g[0], g[1], g[2], g[3]};
      f32x4 v1 = {g[4], g[5], g[6], g[7]};
      *(f32x4*)op = v0;
      *(f32x4*)(op + 4) = v1;
    }
  }
}

// ---------------- fallback (R1, validated): NCHW fp32 in-kernel ----------------
constexpr int LDKF = 40;
__global__ __launch_bounds__(512, 2) void corr_mfma_fb(
    const float* __restrict__ x1, const float* __restrict__ x2, float* __restrict__ out) {
  __shared__ __attribute__((aligned(16))) unsigned short lsA[64 * LDKF];
  __shared__ __attribute__((aligned(16))) unsigned short lsB[NWIN * LDKF];
  const int t = threadIdx.x;
  const int b = blockIdx.y;
  const int ti = blockIdx.x / 12, tj = blockIdx.x % 12;
  const int i0 = ti * TI, j0 = tj * TJ;
  const int lane = t & 63, wv = t >> 6;
  const int mtp = wv >> 2, cg = wv & 3, cbeg = cg * 12;
  const int qk = lane >> 4, lr = lane & 15;
  f32x4 acc[2][13];
#pragma unroll
  for (int a = 0; a < 2; ++a)
#pragma unroll
    for (int cc = 0; cc < 13; ++cc) acc[a][cc] = (f32x4){0.f, 0.f, 0.f, 0.f};
  const int am = t & 63, ak4 = t >> 6;
  const int aii = am >> 3, ajj = am & 7;
  const float* x1p = x1 + ((size_t)b * NC + 4 * ak4) * PLANE + (size_t)(i0 + aii) * IW + (j0 + ajj);
  const float* x2b = x2 + (size_t)b * NC * PLANE;
  for (int ks = 0; ks < NKS; ++ks) {
    __syncthreads();
    {
      const float* p = x1p + (size_t)ks * KC * PLANE;
      us4 v = {f2bf(p[0]), f2bf(p[PLANE]), f2bf(p[2 * PLANE]), f2bf(p[3 * PLANE])};
      *(us4*)&lsA[am * LDKF + 4 * ak4] = v;
    }
    for (int w = t; w < NWIN; w += 512) {
      const int wi = w / WIN, wj = w - wi * WIN;
      const int gi = i0 - RAD + wi, gj = j0 - RAD + wj;
      const bool ok = ((unsigned)gi < (unsigned)IH) && ((unsigned)gj < (unsigned)IW);
      const float* p = x2b + ((size_t)(ks * KC) * IH + gi) * IW + gj;
      unsigned short* dst = &lsB[w * LDKF];
#pragma unroll
      for (int k4 = 0; k4 < 8; ++k4) {
        const float* q = p + (size_t)(4 * k4) * PLANE;
        us4 v = {f2bf(ok ? q[0] : 0.f), f2bf(ok ? q[PLANE] : 0.f),
                 f2bf(ok ? q[2 * PLANE] : 0.f), f2bf(ok ? q[3 * PLANE] : 0.f)};
        *(us4*)&dst[4 * k4] = v;
      }
    }
    __syncthreads();
    short8 a0 = *(const short8*)&lsA[(32 * mtp + lr) * LDKF + 8 * qk];
    short8 a1 = *(const short8*)&lsA[(32 * mtp + 16 + lr) * LDKF + 8 * qk];
#pragma unroll
    for (int cc = 0; cc < 13; ++cc) {
      const int wrow = 16 * (cbeg + cc) + lr;
      short8 bf = *(const short8*)&lsB[wrow * LDKF + 8 * qk];
      acc[0][cc] = __builtin_amdgcn_mfma_f32_16x16x32_bf16(a0, bf, acc[0][cc], 0, 0, 0);
      acc[1][cc] = __builtin_amdgcn_mfma_f32_16x16x32_bf16(a1, bf, acc[1][cc], 0, 0, 0);
    }
  }
#pragma unroll
  for (int a = 0; a < 2; ++a) {
    const int mb = 16 * (2 * mtp + a) + qk * 4;
#pragma unroll
    for (int cc = 0; cc < 13; ++cc) {
      if (cg > 0 && cc == 0) continue;
      const int n = 16 * (cbeg + cc) + lr;
      const int wi = n / WIN, wj = n - wi * WIN;
#pragma unroll
      for (int r = 0; r < 4; ++r) {
        const int m = mb + r;
        const int ii = m >> 3, jj = m & 7;
        const int pi = wi - ii, pj = wj - jj;
        if ((unsigned)pi < (unsigned)PATCH && (unsigned)pj < (unsigned)PATCH)
          out[((((size_t)b * PATCH + pi) * PATCH + pj) * IH + (i0 + ii)) * IW + (j0 + jj)] =
              acc[a][cc][r];
      }
    }
  }
}

extern "C" void kernel_launch(void* const* d_in, const int* in_sizes, int n_in,
                              void* d_out, int out_size, void* d_ws, size_t ws_size,
                              hipStream_t stream) {
  const float* x1 = (const float*)d_in[0];
  const float* x2 = (const float*)d_in[1];
  float* out = (float*)d_out;
  const size_t need = (X1T_ELEMS + X2P_ELEMS) * sizeof(unsigned short);  // ~65.1 MB
  if (ws_size >= need) {
    unsigned short* x1k = (unsigned short*)d_ws;
    unsigned short* x2k = x1k + X1T_ELEMS;
    prepass_kmajor<<<X1BLKS + X2BLKS, 256, 0, stream>>>(x1, x2, x1k, x2k);
    corr_wavepipe2<<<NB * 96, 512, 0, stream>>>(x1k, x2k, out);
  } else {
    dim3 grid(96, NB);
    corr_mfma_fb<<<grid, 512, 0, stream>>>(x1, x2, out);
  }
}

// Round 19
// 82.806 us; speedup vs baseline: 1.0565x; 1.0565x over previous
//
#include <hip/hip_runtime.h>

typedef __attribute__((ext_vector_type(8))) short short8;
typedef __attribute__((ext_vector_type(4))) float f32x4;
typedef __attribute__((ext_vector_type(16))) float f32x16;
typedef __attribute__((ext_vector_type(4))) unsigned short us4;

constexpr int NB = 8, NC = 256, IH = 64, IW = 96;
constexpr int PATCH = 21, RAD = 10;
constexpr int WIN = 28;                  // window j-width (tile j=8 + 20)
constexpr int KC = 32, NKS = NC / KC;    // channel chunking
constexpr int PLANE = IH * IW;
constexpr int PH = IH + 2 * RAD, PW = IW + 2 * RAD;   // 84 x 116 padded x2
// 16x8 pixel tile, window 36 rows split into two 18-row halves per block (R13)
constexpr int NPOS = 512;                // 18*28=504 positions padded to 512
constexpr int NBCH = NPOS * 4;           // 2048 B-chunks / K-step
constexpr int NACH = 512;                // A: 128 px * 32ch / 8per-chunk
constexpr int NCHUNK = NBCH + NACH;      // 2560 chunks = 5 slots x 512 thr
constexpr int ASTR = IH * IW * KC;       // per-ks stride in x1k (elements)
constexpr int BSTR = PH * PW * KC;       // per-ks stride in x2k (elements)
constexpr size_t X1T_ELEMS = (size_t)NB * NKS * ASTR;   // 12.58M
constexpr size_t X2P_ELEMS = (size_t)NB * NKS * BSTR;   // 19.96M
constexpr int GSTR = 129;                // G row stride (floats): bank stride 1
constexpr int X1BLKS = NB * IH * 8;      // 4096 prepass blocks for x1
constexpr int X2BLKS = NB * PH * 8;      // 5376 prepass blocks for x2

__device__ __forceinline__ unsigned short f2bf(float f) {
  unsigned u = __builtin_bit_cast(unsigned, f);
  u += 0x7fffu + ((u >> 16) & 1u);       // RNE
  return (unsigned short)(u >> 16);
}

// ---- merged pre-pass (R16-validated, BW-bound): NCHW fp32 -> K-major bf16 ----
__global__ __launch_bounds__(256) void prepass_kmajor(
    const float* __restrict__ x1, const float* __restrict__ x2,
    unsigned short* __restrict__ x1k, unsigned short* __restrict__ x2k) {
  __shared__ float lsf[32 * 97];
  const int t = threadIdx.x;
  if (blockIdx.x < X1BLKS) {
    const int blk = blockIdx.x;          // b*512 + i*8 + ct
    const int ct = blk & 7, i = (blk >> 3) & 63, b = blk >> 9;
    const int c0 = ct * 32;
    const float* sp = x1 + ((size_t)b * NC + c0) * PLANE + (size_t)i * IW;
#pragma unroll
    for (int k = 0; k < 3; ++k) {        // 768 float4
      int idx = k * 256 + t;
      int c = idx / 24, j4 = idx - c * 24;
      f32x4 v = *(const f32x4*)(sp + (size_t)c * PLANE + 4 * j4);
      float* lp = &lsf[c * 97 + 4 * j4];
      lp[0] = v[0]; lp[1] = v[1]; lp[2] = v[2]; lp[3] = v[3];
    }
    __syncthreads();
    unsigned short* dp = x1k + (((size_t)(b * NKS + ct) * IH + i) * IW) * KC;
#pragma unroll
    for (int k = 0; k < 3; ++k) {
      int o = k * 256 + t;
      int j = o >> 3, cq = o & 7;
      us4 v = {f2bf(lsf[(cq * 4 + 0) * 97 + j]), f2bf(lsf[(cq * 4 + 1) * 97 + j]),
               f2bf(lsf[(cq * 4 + 2) * 97 + j]), f2bf(lsf[(cq * 4 + 3) * 97 + j])};
      *(us4*)&dp[(size_t)j * KC + cq * 4] = v;
    }
  } else {
    const int blk = blockIdx.x - X1BLKS; // b*(84*8) + i*8 + ct
    const int ct = blk & 7, i = (blk >> 3) % PH, b = blk / (PH * 8);
    const int c0 = ct * 32;
    const int isrc = i - RAD;
    const bool rowok = (unsigned)isrc < (unsigned)IH;
    if (rowok) {
      const float* sp = x2 + ((size_t)b * NC + c0) * PLANE + (size_t)isrc * IW;
#pragma unroll
      for (int k = 0; k < 3; ++k) {
        int idx = k * 256 + t;
        int c = idx / 24, j4 = idx - c * 24;
        f32x4 v = *(const f32x4*)(sp + (size_t)c * PLANE + 4 * j4);
        float* lp = &lsf[c * 97 + 4 * j4];
        lp[0] = v[0]; lp[1] = v[1]; lp[2] = v[2]; lp[3] = v[3];
      }
    }
    __syncthreads();
    unsigned short* dp = x2k + (((size_t)(b * NKS + ct) * PH + i) * PW) * KC;
#pragma unroll
    for (int k = 0; k < 4; ++k) {
      int o = k * 256 + t;
      if (o < PW * 8) {
        int j = o >> 3, cq = o & 7;
        int jsrc = j - RAD;
        us4 v = {0, 0, 0, 0};
        if (rowok && (unsigned)jsrc < (unsigned)IW)
          v = us4{f2bf(lsf[(cq * 4 + 0) * 97 + jsrc]), f2bf(lsf[(cq * 4 + 1) * 97 + jsrc]),
                  f2bf(lsf[(cq * 4 + 2) * 97 + jsrc]), f2bf(lsf[(cq * 4 + 3) * 97 + jsrc])};
        *(us4*)&dp[(size_t)j * KC + cq * 4] = v;
      }
    }
  }
}

// ---- main: R13 skeleton (16x8 tile x half-window, triple-buffered gload_lds,
//      vmcnt-before-barrier), COMPUTE switched to v_mfma_f32_32x32x16_bf16:
//      wave owns 2 col-tiles(32 pos) x 4 M-tiles x 2 k-halves = 16 MFMA/K-step.
__global__ __launch_bounds__(512, 2) void corr_half32(
    const unsigned short* __restrict__ x1k, const unsigned short* __restrict__ x2k,
    float* __restrict__ out) {
  __shared__ __attribute__((aligned(16))) unsigned short ls[3 * NCHUNK * 8];  // 122880 B

  const int t = threadIdx.x, lane = t & 63, wv = t >> 6;   // wv 0..7
  const int bid = blockIdx.x;
  const int b = bid & 7;                 // batch -> XCD locality
  const int tile = bid >> 3;             // 0..95
  const int v = tile & 1;                // window half (rows 18v..18v+17)
  const int tt = tile >> 1;              // 0..47
  const int ti = tt / 12, tj = tt % 12;
  const int i0 = 16 * ti, j0 = 8 * tj;
  const int l31 = lane & 31, h2 = lane >> 5;
  const int qk = lane >> 4, lr = lane & 15;   // (staging enumeration only)

  const unsigned short* x1b = x1k + (size_t)b * NKS * ASTR;
  const unsigned short* x2b = x2k + (size_t)b * NKS * BSTR;

  // 5 stage slots x 512 thr (R13-validated): slots 0-3 B (swizzled), slot 4 A
  const unsigned short* srcp[5];
#pragma unroll
  for (int it = 0; it < 5; ++it) {
    int q = it * 512 + t;
    if (q < NBCH) {                       // B: invert slot swizzle (validated form)
      int w = ((q >> 3) << 1) | (((q >> 2) ^ (q >> 4)) & 1);
      int c4 = (q & 3) ^ (w & 3);
      int wd = (w >= 504) ? (w - 504) : w;      // 8 dummy positions replicate
      int wi = wd / WIN, wj = wd - wi * WIN;
      srcp[it] = x2b + ((size_t)(i0 + 18 * v + wi) * PW + (j0 + wj)) * KC + c4 * 8;
    } else {                              // A: same inverse over qa 0..511
      int qa = q - NBCH;
      int m = ((qa >> 3) << 1) | (((qa >> 2) ^ (qa >> 4)) & 1);
      int c4 = (qa & 3) ^ (m & 3);
      srcp[it] = x1b + ((size_t)(i0 + (m >> 3)) * IW + (j0 + (m & 7))) * KC + c4 * 8;
    }
  }
  (void)qk; (void)lr;

  f32x16 acc[2][4];
#pragma unroll
  for (int cc = 0; cc < 2; ++cc)
#pragma unroll
    for (int mt = 0; mt < 4; ++mt)
#pragma unroll
      for (int e = 0; e < 16; ++e) acc[cc][mt][e] = 0.f;

#define STAGE(BUF, KS)                                                              \
  {                                                                                 \
    unsigned short* lb = &ls[(BUF) * NCHUNK * 8];                                   \
    _Pragma("unroll")                                                               \
    for (int it = 0; it < 5; ++it)                                                  \
      __builtin_amdgcn_global_load_lds(                                             \
          (const void*)(srcp[it] + (size_t)(KS) * (it < 4 ? BSTR : ASTR)),          \
          (void*)(lb + (it * 512 + wv * 64) * 8), 16, 0, 0);                        \
  }

// chunk(w,c4) at slot (4w+c4)^(w&7); A chunk(m,c4) at NBCH + ((4m+c4)^(m&7)).
// Per-lane k-slice identical for A and B (c4q = 2h + h2) -> dot product exact
// under any hw k-permutation (sigma argument, validated since R1).
#define COMPUTE(BUF)                                                                \
  {                                                                                 \
    const unsigned short* lb = &ls[(BUF) * NCHUNK * 8];                             \
    short8 afr[4][2];                                                               \
    _Pragma("unroll")                                                               \
    for (int mt = 0; mt < 4; ++mt)                                                  \
      _Pragma("unroll")                                                             \
      for (int h = 0; h < 2; ++h) {                                                 \
        int m = 32 * mt + l31, c4q = 2 * h + h2;                                    \
        afr[mt][h] = *(const short8*)(lb + (NBCH + ((4 * m + c4q) ^ (m & 7))) * 8); \
      }                                                                             \
    _Pragma("unroll")                                                               \
    for (int cc = 0; cc < 2; ++cc) {                                                \
      int wq = 32 * (2 * wv + cc) + l31;                                            \
      _Pragma("unroll")                                                             \
      for (int h = 0; h < 2; ++h) {                                                 \
        int c4q = 2 * h + h2;                                                       \
        short8 bf = *(const short8*)(lb + (((4 * wq + c4q) ^ (wq & 7))) * 8);       \
        _Pragma("unroll")                                                           \
        for (int mt = 0; mt < 4; ++mt)                                              \
          acc[cc][mt] = __builtin_amdgcn_mfma_f32_32x32x16_bf16(afr[mt][h], bf,     \
                                                                acc[cc][mt], 0, 0, 0); \
      }                                                                             \
    }                                                                               \
  }

  // prologue: stage ks=0,1
  STAGE(0, 0)
  STAGE(1, 1)

  // R13-validated ordering, uniform 5 loads/wave/stage: vmcnt(10) drains stage(ks).
#define ITER(KS, VM)                                           \
  if ((KS) < 6) STAGE(((KS) + 2) % 3, (KS) + 2)                \
  asm volatile("s_waitcnt vmcnt(" #VM ")" ::: "memory");       \
  asm volatile("s_barrier" ::: "memory");                      \
  COMPUTE((KS) % 3)                                            \
  asm volatile("s_barrier" ::: "memory");

  ITER(0, 10)
  ITER(1, 10)
  ITER(2, 10)
  ITER(3, 10)
  ITER(4, 10)
  ITER(5, 10)
  ITER(6, 5)
  ITER(7, 0)
#undef ITER
#undef COMPUTE
#undef STAGE

  // ---- epilogue: G transpose in 3 row-passes of 168 (R13 structure) ----
  // 32x32 C/D (m74/m101): col=lane&31 -> position n; row=(reg&3)+8(reg>>2)+4*h2
  // -> pixel m. Whole frag lands in ONE gf row n; half-waves h2=0/1 fill
  // complementary m-halves. GSTR=129 -> bank stride 1: writes & diagonal
  // gather both conflict-free, no XOR swizzle needed.
  float* gf = (float*)ls;
#pragma unroll
  for (int p = 0; p < 3; ++p) {
    __syncthreads();                     // prior reads (staging or pass p-1) done
    const int R0 = 168 * p;
#pragma unroll
    for (int cc = 0; cc < 2; ++cc) {
      int n = 32 * (2 * wv + cc) + l31;
      if (n >= R0 && n < R0 + 168 && n < 504) {
        float* gr = &gf[(n - R0) * GSTR];
#pragma unroll
        for (int mt = 0; mt < 4; ++mt)
#pragma unroll
          for (int q = 0; q < 4; ++q) {
            float* gp = &gr[32 * mt + 8 * q + 4 * h2];
            gp[0] = acc[cc][mt][4 * q + 0];
            gp[1] = acc[cc][mt][4 * q + 1];
            gp[2] = acc[cc][mt][4 * q + 2];
            gp[3] = acc[cc][mt][4 * q + 3];
          }
      }
    }
    __syncthreads();
    // segment decode (R13-validated): W = pi+ii in [18v..18v+18), pass rows
    // rl = n-168p, wi_l = 6p+k; base rl0 = 28k+pj, run rl0..rl0+7.
    int segs = 0;
#pragma unroll
    for (int kk = 0; kk < 6; ++kk) {
      int W = 18 * v + 6 * p + kk;
      int hi = W < 15 ? W : 15, lo = W - 20 > 0 ? W - 20 : 0;
      segs += hi - lo + 1;
    }
    segs *= 21;
    for (int s = t; s < segs; s += 512) {
      int pidx = s / 21, pj = s - pidx * 21;
      int k = 0, rem = pidx, stop = 0;
#pragma unroll
      for (int kk = 0; kk < 5; ++kk) {
        int W = 18 * v + 6 * p + kk;
        int hi = W < 15 ? W : 15, lo = W - 20 > 0 ? W - 20 : 0;
        int c = hi - lo + 1;
        int go = (!stop) && (rem >= c);
        rem -= go ? c : 0;
        k += go;
        stop |= !go;
      }
      int W = 18 * v + 6 * p + k;
      int lo = W - 20 > 0 ? W - 20 : 0;
      int ii = lo + rem;
      int pi = W - ii;
      int rl0 = 28 * k + pj;
      float g[8];
#pragma unroll
      for (int e = 0; e < 8; ++e) g[e] = gf[(rl0 + e) * GSTR + 8 * ii + e];
      float* op = out + ((((size_t)b * PATCH + pi) * PATCH + pj) * IH + (i0 + ii)) * IW + j0;
      f32x4 v0 = {g[0], g[1], g[2], g[3]};
      f32x4 v1 = {g[4], g[5], g[6], g[7]};
      *(f32x4*)op = v0;
      *(f32x4*)(op + 4) = v1;
    }
  }
}

// ---------------- fallback (R1, validated): NCHW fp32 in-kernel ----------------
constexpr int LDKF = 40;
constexpr int NWINF = 784;
__global__ __launch_bounds__(512, 2) void corr_mfma_fb(
    const float* __restrict__ x1, const float* __restrict__ x2, float* __restrict__ out) {
  __shared__ __attribute__((aligned(16))) unsigned short lsA[64 * LDKF];
  __shared__ __attribute__((aligned(16))) unsigned short lsB[NWINF * LDKF];
  const int t = threadIdx.x;
  const int b = blockIdx.y;
  const int ti = blockIdx.x / 12, tj = blockIdx.x % 12;
  const int i0 = ti * 8, j0 = tj * 8;
  const int lane = t & 63, wv = t >> 6;
  const int mtp = wv >> 2, cg = wv & 3, cbeg = cg * 12;
  const int qk = lane >> 4, lr = lane & 15;
  f32x4 acc[2][13];
#pragma unroll
  for (int a = 0; a < 2; ++a)
#pragma unroll
    for (int cc = 0; cc < 13; ++cc) acc[a][cc] = (f32x4){0.f, 0.f, 0.f, 0.f};
  const int am = t & 63, ak4 = t >> 6;
  const int aii = am >> 3, ajj = am & 7;
  const float* x1p = x1 + ((size_t)b * NC + 4 * ak4) * PLANE + (size_t)(i0 + aii) * IW + (j0 + ajj);
  const float* x2b = x2 + (size_t)b * NC * PLANE;
  for (int ks = 0; ks < NKS; ++ks) {
    __syncthreads();
    {
      const float* p = x1p + (size_t)ks * KC * PLANE;
      us4 v = {f2bf(p[0]), f2bf(p[PLANE]), f2bf(p[2 * PLANE]), f2bf(p[3 * PLANE])};
      *(us4*)&lsA[am * LDKF + 4 * ak4] = v;
    }
    for (int w = t; w < NWINF; w += 512) {
      const int wi = w / WIN, wj = w - wi * WIN;
      const int gi = i0 - RAD + wi, gj = j0 - RAD + wj;
      const bool ok = ((unsigned)gi < (unsigned)IH) && ((unsigned)gj < (unsigned)IW);
      const float* p = x2b + ((size_t)(ks * KC) * IH + gi) * IW + gj;
      unsigned short* dst = &lsB[w * LDKF];
#pragma unroll
      for (int k4 = 0; k4 < 8; ++k4) {
        const float* q = p + (size_t)(4 * k4) * PLANE;
        us4 v = {f2bf(ok ? q[0] : 0.f), f2bf(ok ? q[PLANE] : 0.f),
                 f2bf(ok ? q[2 * PLANE] : 0.f), f2bf(ok ? q[3 * PLANE] : 0.f)};
        *(us4*)&dst[4 * k4] = v;
      }
    }
    __syncthreads();
    short8 a0 = *(const short8*)&lsA[(32 * mtp + lr) * LDKF + 8 * qk];
    short8 a1 = *(const short8*)&lsA[(32 * mtp + 16 + lr) * LDKF + 8 * qk];
#pragma unroll
    for (int cc = 0; cc < 13; ++cc) {
      const int wrow = 16 * (cbeg + cc) + lr;
      short8 bf = *(const short8*)&lsB[wrow * LDKF + 8 * qk];
      acc[0][cc] = __builtin_amdgcn_mfma_f32_16x16x32_bf16(a0, bf, acc[0][cc], 0, 0, 0);
      acc[1][cc] = __builtin_amdgcn_mfma_f32_16x16x32_bf16(a1, bf, acc[1][cc], 0, 0, 0);
    }
  }
#pragma unroll
  for (int a = 0; a < 2; ++a) {
    const int mb = 16 * (2 * mtp + a) + qk * 4;
#pragma unroll
    for (int cc = 0; cc < 13; ++cc) {
      if (cg > 0 && cc == 0) continue;
      const int n = 16 * (cbeg + cc) + lr;
      const int wi = n / WIN, wj = n - wi * WIN;
#pragma unroll
      for (int r = 0; r < 4; ++r) {
        const int m = mb + r;
        const int ii = m >> 3, jj = m & 7;
        const int pi = wi - ii, pj = wj - jj;
        if ((unsigned)pi < (unsigned)PATCH && (unsigned)pj < (unsigned)PATCH)
          out[((((size_t)b * PATCH + pi) * PATCH + pj) * IH + (i0 + ii)) * IW + (j0 + jj)] =
              acc[a][cc][r];
      }
    }
  }
}

extern "C" void kernel_launch(void* const* d_in, const int* in_sizes, int n_in,
                              void* d_out, int out_size, void* d_ws, size_t ws_size,
                              hipStream_t stream) {
  const float* x1 = (const float*)d_in[0];
  const float* x2 = (const float*)d_in[1];
  float* out = (float*)d_out;
  const size_t need = (X1T_ELEMS + X2P_ELEMS) * sizeof(unsigned short);  // ~65.1 MB
  if (ws_size >= need) {
    unsigned short* x1k = (unsigned short*)d_ws;
    unsigned short* x2k = x1k + X1T_ELEMS;
    prepass_kmajor<<<X1BLKS + X2BLKS, 256, 0, stream>>>(x1, x2, x1k, x2k);
    corr_half32<<<NB * 96, 512, 0, stream>>>(x1k, x2k, out);
  } else {
    dim3 grid(96, NB);
    corr_mfma_fb<<<grid, 512, 0, stream>>>(x1, x2, out);
  }
}

// Round 20
// 79.700 us; speedup vs baseline: 1.0977x; 1.0390x over previous
//
#include <hip/hip_runtime.h>

typedef __attribute__((ext_vector_type(8))) short short8;
typedef __attribute__((ext_vector_type(4))) float f32x4;
typedef __attribute__((ext_vector_type(16))) float f32x16;
typedef __attribute__((ext_vector_type(4))) unsigned short us4;

constexpr int NB = 8, NC = 256, IH = 64, IW = 96;
constexpr int PATCH = 21, RAD = 10;
constexpr int WIN = 28;                  // window j-width (tile j=8 + 20)
constexpr int KC = 32, NKS = NC / KC;    // channel chunking
constexpr int PLANE = IH * IW;
// 16x8 pixel tile, window 36 rows split into two 18-row halves per block (R13/R19)
constexpr int NPOS = 512;                // 18*28=504 positions padded to 512
constexpr int NBCH = NPOS * 4;           // 2048 B-chunks / K-step
constexpr int NACH = 512;                // A: 128 px * 32ch / 8per-chunk
constexpr int NCHUNK = NBCH + NACH;      // 2560 chunks = 5 slots x 512 thr
constexpr int ASTR = IH * IW * KC;       // per-ks stride in BOTH x1k and x2k (unpadded)
constexpr size_t XT_ELEMS = (size_t)NB * NKS * ASTR;   // 12.58M per tensor
constexpr int GSTR = 129;                // G row stride (floats): bank stride 1
constexpr int XBLKS = NB * IH * 8;       // 4096 prepass blocks per tensor

__device__ __forceinline__ unsigned short f2bf(float f) {
  unsigned u = __builtin_bit_cast(unsigned, f);
  u += 0x7fffu + ((u >> 16) & 1u);       // RNE
  return (unsigned short)(u >> 16);
}

// ---- merged pre-pass: NCHW fp32 -> K-major [b][ks][i][j][32] bf16, BOTH tensors
// (R16-validated body; x2 now unpadded = same body as x1). Also zeroes the
// 64B zero-page used by the main kernel's OOB lanes.
__global__ __launch_bounds__(256) void prepass_kmajor(
    const float* __restrict__ x1, const float* __restrict__ x2,
    unsigned short* __restrict__ x1k, unsigned short* __restrict__ x2k,
    unsigned short* __restrict__ zp) {
  __shared__ float lsf[32 * 97];
  const int t = threadIdx.x;
  if (blockIdx.x == 0 && t < 32) zp[t] = 0;   // 64B zero page, every launch
  const bool is2 = blockIdx.x >= XBLKS;
  const int blk = is2 ? (blockIdx.x - XBLKS) : blockIdx.x;   // b*512 + i*8 + ct
  const float* src = is2 ? x2 : x1;
  unsigned short* dst = is2 ? x2k : x1k;
  const int ct = blk & 7, i = (blk >> 3) & 63, b = blk >> 9;
  const int c0 = ct * 32;
  const float* sp = src + ((size_t)b * NC + c0) * PLANE + (size_t)i * IW;
#pragma unroll
  for (int k = 0; k < 3; ++k) {          // 768 float4
    int idx = k * 256 + t;
    int c = idx / 24, j4 = idx - c * 24;
    f32x4 v = *(const f32x4*)(sp + (size_t)c * PLANE + 4 * j4);
    float* lp = &lsf[c * 97 + 4 * j4];
    lp[0] = v[0]; lp[1] = v[1]; lp[2] = v[2]; lp[3] = v[3];
  }
  __syncthreads();
  unsigned short* dp = dst + (((size_t)(b * NKS + ct) * IH + i) * IW) * KC;
#pragma unroll
  for (int k = 0; k < 3; ++k) {          // 96 j x 8 cq -> contiguous 8B writes
    int o = k * 256 + t;
    int j = o >> 3, cq = o & 7;
    us4 v = {f2bf(lsf[(cq * 4 + 0) * 97 + j]), f2bf(lsf[(cq * 4 + 1) * 97 + j]),
             f2bf(lsf[(cq * 4 + 2) * 97 + j]), f2bf(lsf[(cq * 4 + 3) * 97 + j])};
    *(us4*)&dp[(size_t)j * KC + cq * 4] = v;
  }
}

// ---- main: R19 kernel verbatim except srcp setup -- x2 unpadded, OOB lanes
// point at the zero page with per-lane stride 0 (gload_lds source is per-lane).
__global__ __launch_bounds__(512, 2) void corr_half32(
    const unsigned short* __restrict__ x1k, const unsigned short* __restrict__ x2k,
    const unsigned short* __restrict__ zp, float* __restrict__ out) {
  __shared__ __attribute__((aligned(16))) unsigned short ls[3 * NCHUNK * 8];  // 122880 B

  const int t = threadIdx.x, lane = t & 63, wv = t >> 6;   // wv 0..7
  const int bid = blockIdx.x;
  const int b = bid & 7;                 // batch -> XCD locality
  const int tile = bid >> 3;             // 0..95
  const int v = tile & 1;                // window half (rows 18v..18v+17)
  const int tt = tile >> 1;              // 0..47
  const int ti = tt / 12, tj = tt % 12;
  const int i0 = 16 * ti, j0 = 8 * tj;
  const int l31 = lane & 31, h2 = lane >> 5;

  const unsigned short* x1b = x1k + (size_t)b * NKS * ASTR;
  const unsigned short* x2b = x2k + (size_t)b * NKS * ASTR;

  // 5 stage slots x 512 thr: slots 0-3 B (swizzled; OOB/pad -> zero page,
  // stride 0), slot 4 A. All addresses and strides are per-lane VGPRs.
  const unsigned short* srcp[5];
  int sstp[5];
#pragma unroll
  for (int it = 0; it < 5; ++it) {
    int q = it * 512 + t;
    if (q < NBCH) {                       // B: invert slot swizzle (validated form)
      int w = ((q >> 3) << 1) | (((q >> 2) ^ (q >> 4)) & 1);
      int c4 = (q & 3) ^ (w & 3);
      bool pad = (w >= 504);
      int wd = pad ? 0 : w;
      int wi = wd / WIN, wj = wd - wi * WIN;
      int gi = i0 + 18 * v + wi - RAD;    // source row in unpadded x2
      int gj = j0 + wj - RAD;
      bool ok = !pad && ((unsigned)gi < (unsigned)IH) && ((unsigned)gj < (unsigned)IW);
      srcp[it] = ok ? (x2b + ((size_t)gi * IW + gj) * KC + c4 * 8) : zp;
      sstp[it] = ok ? ASTR : 0;
    } else {                              // A: same inverse over qa 0..511
      int qa = q - NBCH;
      int m = ((qa >> 3) << 1) | (((qa >> 2) ^ (qa >> 4)) & 1);
      int c4 = (qa & 3) ^ (m & 3);
      srcp[it] = x1b + ((size_t)(i0 + (m >> 3)) * IW + (j0 + (m & 7))) * KC + c4 * 8;
      sstp[it] = ASTR;
    }
  }

  f32x16 acc[2][4];
#pragma unroll
  for (int cc = 0; cc < 2; ++cc)
#pragma unroll
    for (int mt = 0; mt < 4; ++mt)
#pragma unroll
      for (int e = 0; e < 16; ++e) acc[cc][mt][e] = 0.f;

#define STAGE(BUF, KS)                                                              \
  {                                                                                 \
    unsigned short* lb = &ls[(BUF) * NCHUNK * 8];                                   \
    _Pragma("unroll")                                                               \
    for (int it = 0; it < 5; ++it)                                                  \
      __builtin_amdgcn_global_load_lds(                                             \
          (const void*)(srcp[it] + (size_t)(KS) * sstp[it]),                        \
          (void*)(lb + (it * 512 + wv * 64) * 8), 16, 0, 0);                        \
  }

// chunk(w,c4) at slot (4w+c4)^(w&7); A chunk(m,c4) at NBCH + ((4m+c4)^(m&7)).
// Per-lane k-slice identical for A and B (c4q = 2h + h2) -> dot product exact
// under any hw k-permutation (sigma argument, validated since R1).
#define COMPUTE(BUF)                                                                \
  {                                                                                 \
    const unsigned short* lb = &ls[(BUF) * NCHUNK * 8];                             \
    short8 afr[4][2];                                                               \
    _Pragma("unroll")                                                               \
    for (int mt = 0; mt < 4; ++mt)                                                  \
      _Pragma("unroll")                                                             \
      for (int h = 0; h < 2; ++h) {                                                 \
        int m = 32 * mt + l31, c4q = 2 * h + h2;                                    \
        afr[mt][h] = *(const short8*)(lb + (NBCH + ((4 * m + c4q) ^ (m & 7))) * 8); \
      }                                                                             \
    _Pragma("unroll")                                                               \
    for (int cc = 0; cc < 2; ++cc) {                                                \
      int wq = 32 * (2 * wv + cc) + l31;                                            \
      _Pragma("unroll")                                                             \
      for (int h = 0; h < 2; ++h) {                                                 \
        int c4q = 2 * h + h2;                                                       \
        short8 bf = *(const short8*)(lb + (((4 * wq + c4q) ^ (wq & 7))) * 8);       \
        _Pragma("unroll")                                                           \
        for (int mt = 0; mt < 4; ++mt)                                              \
          acc[cc][mt] = __builtin_amdgcn_mfma_f32_32x32x16_bf16(afr[mt][h], bf,     \
                                                                acc[cc][mt], 0, 0, 0); \
      }                                                                             \
    }                                                                               \
  }

  // prologue: stage ks=0,1
  STAGE(0, 0)
  STAGE(1, 1)

  // R13/R19-validated ordering, uniform 5 loads/wave/stage: vmcnt(10) drains stage(ks).
#define ITER(KS, VM)                                           \
  if ((KS) < 6) STAGE(((KS) + 2) % 3, (KS) + 2)                \
  asm volatile("s_waitcnt vmcnt(" #VM ")" ::: "memory");       \
  asm volatile("s_barrier" ::: "memory");                      \
  COMPUTE((KS) % 3)                                            \
  asm volatile("s_barrier" ::: "memory");

  ITER(0, 10)
  ITER(1, 10)
  ITER(2, 10)
  ITER(3, 10)
  ITER(4, 10)
  ITER(5, 10)
  ITER(6, 5)
  ITER(7, 0)
#undef ITER
#undef COMPUTE
#undef STAGE

  // ---- epilogue: G transpose in 3 row-passes of 168 (R19-validated) ----
  // 32x32 C/D (m74/m101): col=lane&31 -> position n; row=(reg&3)+8(reg>>2)+4*h2
  // -> pixel m. GSTR=129 -> bank stride 1: writes & diagonal gather conflict-free.
  float* gf = (float*)ls;
#pragma unroll
  for (int p = 0; p < 3; ++p) {
    __syncthreads();                     // prior reads (staging or pass p-1) done
    const int R0 = 168 * p;
#pragma unroll
    for (int cc = 0; cc < 2; ++cc) {
      int n = 32 * (2 * wv + cc) + l31;
      if (n >= R0 && n < R0 + 168 && n < 504) {
        float* gr = &gf[(n - R0) * GSTR];
#pragma unroll
        for (int mt = 0; mt < 4; ++mt)
#pragma unroll
          for (int q = 0; q < 4; ++q) {
            float* gp = &gr[32 * mt + 8 * q + 4 * h2];
            gp[0] = acc[cc][mt][4 * q + 0];
            gp[1] = acc[cc][mt][4 * q + 1];
            gp[2] = acc[cc][mt][4 * q + 2];
            gp[3] = acc[cc][mt][4 * q + 3];
          }
      }
    }
    __syncthreads();
    // segment decode (R13/R19-validated): W = pi+ii in [18v..18v+18)
    int segs = 0;
#pragma unroll
    for (int kk = 0; kk < 6; ++kk) {
      int W = 18 * v + 6 * p + kk;
      int hi = W < 15 ? W : 15, lo = W - 20 > 0 ? W - 20 : 0;
      segs += hi - lo + 1;
    }
    segs *= 21;
    for (int s = t; s < segs; s += 512) {
      int pidx = s / 21, pj = s - pidx * 21;
      int k = 0, rem = pidx, stop = 0;
#pragma unroll
      for (int kk = 0; kk < 5; ++kk) {
        int W = 18 * v + 6 * p + kk;
        int hi = W < 15 ? W : 15, lo = W - 20 > 0 ? W - 20 : 0;
        int c = hi - lo + 1;
        int go = (!stop) && (rem >= c);
        rem -= go ? c : 0;
        k += go;
        stop |= !go;
      }
      int W = 18 * v + 6 * p + k;
      int lo = W - 20 > 0 ? W - 20 : 0;
      int ii = lo + rem;
      int pi = W - ii;
      int rl0 = 28 * k + pj;
      float g[8];
#pragma unroll
      for (int e = 0; e < 8; ++e) g[e] = gf[(rl0 + e) * GSTR + 8 * ii + e];
      float* op = out + ((((size_t)b * PATCH + pi) * PATCH + pj) * IH + (i0 + ii)) * IW + j0;
      f32x4 v0 = {g[0], g[1], g[2], g[3]};
      f32x4 v1 = {g[4], g[5], g[6], g[7]};
      *(f32x4*)op = v0;
      *(f32x4*)(op + 4) = v1;
    }
  }
}

// ---------------- fallback (R1, validated): NCHW fp32 in-kernel ----------------
constexpr int LDKF = 40;
constexpr int NWINF = 784;
__global__ __launch_bounds__(512, 2) void corr_mfma_fb(
    const float* __restrict__ x1, const float* __restrict__ x2, float* __restrict__ out) {
  __shared__ __attribute__((aligned(16))) unsigned short lsA[64 * LDKF];
  __shared__ __attribute__((aligned(16))) unsigned short lsB[NWINF * LDKF];
  const int t = threadIdx.x;
  const int b = blockIdx.y;
  const int ti = blockIdx.x / 12, tj = blockIdx.x % 12;
  const int i0 = ti * 8, j0 = tj * 8;
  const int lane = t & 63, wv = t >> 6;
  const int mtp = wv >> 2, cg = wv & 3, cbeg = cg * 12;
  const int qk = lane >> 4, lr = lane & 15;
  f32x4 acc[2][13];
#pragma unroll
  for (int a = 0; a < 2; ++a)
#pragma unroll
    for (int cc = 0; cc < 13; ++cc) acc[a][cc] = (f32x4){0.f, 0.f, 0.f, 0.f};
  const int am = t & 63, ak4 = t >> 6;
  const int aii = am >> 3, ajj = am & 7;
  const float* x1p = x1 + ((size_t)b * NC + 4 * ak4) * PLANE + (size_t)(i0 + aii) * IW + (j0 + ajj);
  const float* x2b = x2 + (size_t)b * NC * PLANE;
  for (int ks = 0; ks < NKS; ++ks) {
    __syncthreads();
    {
      const float* p = x1p + (size_t)ks * KC * PLANE;
      us4 v = {f2bf(p[0]), f2bf(p[PLANE]), f2bf(p[2 * PLANE]), f2bf(p[3 * PLANE])};
      *(us4*)&lsA[am * LDKF + 4 * ak4] = v;
    }
    for (int w = t; w < NWINF; w += 512) {
      const int wi = w / WIN, wj = w - wi * WIN;
      const int gi = i0 - RAD + wi, gj = j0 - RAD + wj;
      const bool ok = ((unsigned)gi < (unsigned)IH) && ((unsigned)gj < (unsigned)IW);
      const float* p = x2b + ((size_t)(ks * KC) * IH + gi) * IW + gj;
      unsigned short* dst = &lsB[w * LDKF];
#pragma unroll
      for (int k4 = 0; k4 < 8; ++k4) {
        const float* q = p + (size_t)(4 * k4) * PLANE;
        us4 v = {f2bf(ok ? q[0] : 0.f), f2bf(ok ? q[PLANE] : 0.f),
                 f2bf(ok ? q[2 * PLANE] : 0.f), f2bf(ok ? q[3 * PLANE] : 0.f)};
        *(us4*)&dst[4 * k4] = v;
      }
    }
    __syncthreads();
    short8 a0 = *(const short8*)&lsA[(32 * mtp + lr) * LDKF + 8 * qk];
    short8 a1 = *(const short8*)&lsA[(32 * mtp + 16 + lr) * LDKF + 8 * qk];
#pragma unroll
    for (int cc = 0; cc < 13; ++cc) {
      const int wrow = 16 * (cbeg + cc) + lr;
      short8 bf = *(const short8*)&lsB[wrow * LDKF + 8 * qk];
      acc[0][cc] = __builtin_amdgcn_mfma_f32_16x16x32_bf16(a0, bf, acc[0][cc], 0, 0, 0);
      acc[1][cc] = __builtin_amdgcn_mfma_f32_16x16x32_bf16(a1, bf, acc[1][cc], 0, 0, 0);
    }
  }
#pragma unroll
  for (int a = 0; a < 2; ++a) {
    const int mb = 16 * (2 * mtp + a) + qk * 4;
#pragma unroll
    for (int cc = 0; cc < 13; ++cc) {
      if (cg > 0 && cc == 0) continue;
      const int n = 16 * (cbeg + cc) + lr;
      const int wi = n / WIN, wj = n - wi * WIN;
#pragma unroll
      for (int r = 0; r < 4; ++r) {
        const int m = mb + r;
        const int ii = m >> 3, jj = m & 7;
        const int pi = wi - ii, pj = wj - jj;
        if ((unsigned)pi < (unsigned)PATCH && (unsigned)pj < (unsigned)PATCH)
          out[((((size_t)b * PATCH + pi) * PATCH + pj) * IH + (i0 + ii)) * IW + (j0 + jj)] =
              acc[a][cc][r];
      }
    }
  }
}

extern "C" void kernel_launch(void* const* d_in, const int* in_sizes, int n_in,
                              void* d_out, int out_size, void* d_ws, size_t ws_size,
                              hipStream_t stream) {
  const float* x1 = (const float*)d_in[0];
  const float* x2 = (const float*)d_in[1];
  float* out = (float*)d_out;
  const size_t need = 2 * XT_ELEMS * sizeof(unsigned short) + 64;   // ~50.3 MB
  if (ws_size >= need) {
    unsigned short* x1k = (unsigned short*)d_ws;
    unsigned short* x2k = x1k + XT_ELEMS;
    unsigned short* zp = x2k + XT_ELEMS;   // 64B zero page
    prepass_kmajor<<<2 * XBLKS, 256, 0, stream>>>(x1, x2, x1k, x2k, zp);
    corr_half32<<<NB * 96, 512, 0, stream>>>(x1k, x2k, zp, out);
  } else {
    dim3 grid(96, NB);
    corr_mfma_fb<<<grid, 512, 0, stream>>>(x1, x2, out);
  }
}